// Round 6
// baseline (247.271 us; speedup 1.0000x reference)
//
#include <hip/hip_runtime.h>
#include <hip/hip_bf16.h>
#include <stdint.h>

typedef __bf16 bf16;
typedef __attribute__((ext_vector_type(8))) __bf16 bf16x8;
typedef __attribute__((ext_vector_type(4))) float f32x4;

#define SEQ 2048
#define DIM 2048
#define NHEAD 32
#define HD 64
#define ATT_SCALE 0.125f

__device__ __forceinline__ void gload16(void* lds, const void* g) {
  __builtin_amdgcn_global_load_lds(
      (const __attribute__((address_space(1))) unsigned int*)g,
      (__attribute__((address_space(3))) unsigned int*)lds, 16, 0, 0);
}

__device__ __forceinline__ f32x4 mfma16(bf16x8 a, bf16x8 b, f32x4 c) {
  return __builtin_amdgcn_mfma_f32_16x16x32_bf16(a, b, c, 0, 0, 0);
}

// ---------------- elementwise f32 -> bf16 ----------------
__global__ __launch_bounds__(256) void cvt_hs(const float* __restrict__ in,
                                              bf16* __restrict__ out) {
  size_t i = ((size_t)blockIdx.x * 256 + threadIdx.x) * 8;
  f32x4 a = *(const f32x4*)(in + i);
  f32x4 b = *(const f32x4*)(in + i + 4);
  bf16x8 o;
#pragma unroll
  for (int j = 0; j < 4; ++j) { o[j] = (bf16)a[j]; o[j + 4] = (bf16)b[j]; }
  *(bf16x8*)(out + i) = o;
}

// ---------------- weight transpose + convert: wT[n][k] = bf16(w[k][n]) ----------------
__global__ __launch_bounds__(256) void wtrans(
    const float* __restrict__ w0, const float* __restrict__ w1,
    const float* __restrict__ w2, const float* __restrict__ w3,
    bf16* __restrict__ t0, bf16* __restrict__ t1,
    bf16* __restrict__ t2, bf16* __restrict__ t3) {
  const float* wsrc[4] = {w0, w1, w2, w3};
  bf16* wdst[4] = {t0, t1, t2, t3};
  const float* w = wsrc[blockIdx.z];
  bf16* wT = wdst[blockIdx.z];
  __shared__ alignas(16) bf16 tile[64][72];
  int t = threadIdx.x;
  int n0 = blockIdx.x * 64, k0 = blockIdx.y * 64;
#pragma unroll
  for (int i = 0; i < 4; ++i) {
    int r = (t >> 4) + 16 * i;       // k offset
    int c = (t & 15) * 4;            // n offset
    f32x4 v = *(const f32x4*)(w + (size_t)(k0 + r) * DIM + n0 + c);
#pragma unroll
    for (int j = 0; j < 4; ++j) tile[r][c + j] = (bf16)v[j];
  }
  __syncthreads();
#pragma unroll
  for (int i = 0; i < 2; ++i) {
    int n = (t >> 3) + 32 * i;
    int kb = (t & 7) * 8;
    bf16x8 o;
#pragma unroll
    for (int j = 0; j < 8; ++j) o[j] = tile[kb + j][n];
    *(bf16x8*)(wT + (size_t)(n0 + n) * DIM + k0 + kb) = o;
  }
}

// ---------------- 128x128 bf16 GEMM, C = A @ Bt^T  (A: MxK, Bt: NxK) ----------------
template <typename OutT>
__global__ __launch_bounds__(256) void gemm128(
    const bf16* __restrict__ A,
    const bf16* __restrict__ B0, const bf16* __restrict__ B1, const bf16* __restrict__ B2,
    OutT* __restrict__ C0, OutT* __restrict__ C1, OutT* __restrict__ C2,
    int M, int N, int K) {
  const bf16* Bt; OutT* C;
  if (blockIdx.z == 0)      { Bt = B0; C = C0; }
  else if (blockIdx.z == 1) { Bt = B1; C = C1; }
  else                      { Bt = B2; C = C2; }
  __shared__ alignas(16) bf16 As[128][64];
  __shared__ alignas(16) bf16 Bs[128][64];
  int tid = threadIdx.x, lane = tid & 63, w = tid >> 6;
  int wr = w >> 1, wc = w & 1;
  size_t mBase = (size_t)blockIdx.y * 128, nBase = (size_t)blockIdx.x * 128;
  f32x4 acc[4][4] = {};
  int r0 = tid >> 3, sl = tid & 7;
  int lr = lane & 15, hi = lane >> 4, sw = lr & 7;
  for (int kt = 0; kt < K; kt += 64) {
#pragma unroll
    for (int i = 0; i < 4; ++i) {
      int row = r0 + 32 * i;
      int kc = sl ^ (row & 7);
      gload16(&As[row][sl * 8], A + (mBase + row) * K + kt + kc * 8);
      gload16(&Bs[row][sl * 8], Bt + (nBase + row) * K + kt + kc * 8);
    }
    __syncthreads();
#pragma unroll
    for (int kk = 0; kk < 2; ++kk) {
      int cb = kk * 4 + hi;
      bf16x8 a[4], b[4];
#pragma unroll
      for (int m = 0; m < 4; ++m)
        a[m] = *(const bf16x8*)&As[wr * 64 + m * 16 + lr][(cb ^ sw) * 8];
#pragma unroll
      for (int n = 0; n < 4; ++n)
        b[n] = *(const bf16x8*)&Bs[wc * 64 + n * 16 + lr][(cb ^ sw) * 8];
#pragma unroll
      for (int m = 0; m < 4; ++m)
#pragma unroll
        for (int n = 0; n < 4; ++n)
          acc[m][n] = mfma16(a[m], b[n], acc[m][n]);
    }
    __syncthreads();
  }
#pragma unroll
  for (int m = 0; m < 4; ++m)
#pragma unroll
    for (int n = 0; n < 4; ++n)
#pragma unroll
      for (int j = 0; j < 4; ++j) {
        size_t row = mBase + wr * 64 + m * 16 + hi * 4 + j;
        size_t col = nBase + wc * 64 + n * 16 + lr;
        C[row * N + col] = (OutT)acc[m][n][j];
      }
}

// ---- split-K (x2) variant for the 2048x2048 out-projection: 512 blocks ----
__global__ __launch_bounds__(256) void gemm_osk(
    const bf16* __restrict__ A, const bf16* __restrict__ Bt,
    float* __restrict__ P0, float* __restrict__ P1) {
  const int K = DIM, N = DIM;
  float* C = blockIdx.z ? P1 : P0;
  int kbeg = blockIdx.z * (K / 2), kend = kbeg + K / 2;
  __shared__ alignas(16) bf16 As[128][64];
  __shared__ alignas(16) bf16 Bs[128][64];
  int tid = threadIdx.x, lane = tid & 63, w = tid >> 6;
  int wr = w >> 1, wc = w & 1;
  size_t mBase = (size_t)blockIdx.y * 128, nBase = (size_t)blockIdx.x * 128;
  f32x4 acc[4][4] = {};
  int r0 = tid >> 3, sl = tid & 7;
  int lr = lane & 15, hi = lane >> 4, sw = lr & 7;
  for (int kt = kbeg; kt < kend; kt += 64) {
#pragma unroll
    for (int i = 0; i < 4; ++i) {
      int row = r0 + 32 * i;
      int kc = sl ^ (row & 7);
      gload16(&As[row][sl * 8], A + (mBase + row) * K + kt + kc * 8);
      gload16(&Bs[row][sl * 8], Bt + (nBase + row) * K + kt + kc * 8);
    }
    __syncthreads();
#pragma unroll
    for (int kk = 0; kk < 2; ++kk) {
      int cb = kk * 4 + hi;
      bf16x8 a[4], b[4];
#pragma unroll
      for (int m = 0; m < 4; ++m)
        a[m] = *(const bf16x8*)&As[wr * 64 + m * 16 + lr][(cb ^ sw) * 8];
#pragma unroll
      for (int n = 0; n < 4; ++n)
        b[n] = *(const bf16x8*)&Bs[wc * 64 + n * 16 + lr][(cb ^ sw) * 8];
#pragma unroll
      for (int m = 0; m < 4; ++m)
#pragma unroll
        for (int n = 0; n < 4; ++n)
          acc[m][n] = mfma16(a[m], b[n], acc[m][n]);
    }
    __syncthreads();
  }
#pragma unroll
  for (int m = 0; m < 4; ++m)
#pragma unroll
    for (int n = 0; n < 4; ++n)
#pragma unroll
      for (int j = 0; j < 4; ++j) {
        size_t row = mBase + wr * 64 + m * 16 + hi * 4 + j;
        size_t col = nBase + wc * 64 + n * 16 + lr;
        C[row * N + col] = acc[m][n][j];
      }
}

// ---- y = p0 + p1 (split-K reduce), vectorized ----
__global__ __launch_bounds__(256) void addp(const float* __restrict__ a,
                                            const float* __restrict__ b,
                                            float* __restrict__ y) {
  size_t i = ((size_t)blockIdx.x * 256 + threadIdx.x) * 4;
  f32x4 va = *(const f32x4*)(a + i);
  f32x4 vb = *(const f32x4*)(b + i);
  *(f32x4*)(y + i) = va + vb;
}

// ---------------- RoPE for q,k + k blend; writes head-major bf16 + f32 k out ----------------
__global__ __launch_bounds__(256) void ropeqk(
    const bf16* __restrict__ qraw, const bf16* __restrict__ kraw,
    const float* __restrict__ fc, const float* __restrict__ fs,
    const float* __restrict__ kcache, const float* __restrict__ kmask,
    float* __restrict__ kout, bf16* __restrict__ qb, bf16* __restrict__ kb) {
  int s = blockIdx.x;
  float km = kmask[s];
  float omk = 1.0f - km;
  for (int p = threadIdx.x; p < DIM / 2; p += 256) {
    int h = p >> 5, i = p & 31;
    float c = fc[s * 32 + i], sn = fs[s * 32 + i];
    size_t src = (size_t)s * DIM + h * 64 + 2 * i;
    float xr = (float)qraw[src], xi = (float)qraw[src + 1];
    float q0v = xr * c - xi * sn, q1v = xr * sn + xi * c;
    size_t dsth = (size_t)h * SEQ * HD + (size_t)s * HD + 2 * i;
    qb[dsth] = (bf16)q0v; qb[dsth + 1] = (bf16)q1v;
    xr = (float)kraw[src]; xi = (float)kraw[src + 1];
    float k0v = xr * c - xi * sn, k1v = xr * sn + xi * c;
    float b0 = kcache[src] * omk + k0v * km;
    float b1 = kcache[src + 1] * omk + k1v * km;
    kout[src] = b0; kout[src + 1] = b1;
    kb[dsth] = (bf16)b0; kb[dsth + 1] = (bf16)b1;
  }
}

// ---------------- v blend + f32 out + per-head transpose to vT[h][hd][s] ----------------
__global__ __launch_bounds__(256) void vprep(
    const bf16* __restrict__ vraw, const float* __restrict__ vcache,
    const float* __restrict__ vmask, float* __restrict__ vout,
    bf16* __restrict__ vtb) {
  int h = blockIdx.y;
  int s0 = blockIdx.x * 64;
  __shared__ alignas(16) bf16 tile[64][72];
  int t = threadIdx.x;
#pragma unroll
  for (int i = 0; i < 4; ++i) {
    int r = (t >> 4) + 16 * i;   // s offset
    int c = (t & 15) * 4;        // hd offset
    int s = s0 + r;
    float vm = vmask[s], om = 1.0f - vm;
    size_t src = (size_t)s * DIM + h * 64 + c;
    f32x4 vc = *(const f32x4*)(vcache + src);
    f32x4 o;
#pragma unroll
    for (int j = 0; j < 4; ++j) {
      float val = vc[j] * om + (float)vraw[src + j] * vm;
      o[j] = val;
      tile[r][c + j] = (bf16)val;
    }
    *(f32x4*)(vout + src) = o;
  }
  __syncthreads();
#pragma unroll
  for (int i = 0; i < 2; ++i) {
    int hd = (t >> 3) + 32 * i;
    int cb = (t & 7) * 8;
    bf16x8 o;
#pragma unroll
    for (int j = 0; j < 8; ++j) o[j] = tile[cb + j][hd];
    *(bf16x8*)(vtb + (size_t)h * HD * SEQ + (size_t)hd * SEQ + s0 + cb) = o;
  }
}

// ---------------- causal flash attention: paired q-tiles, uniform work ----
// qb,kb: [NHEAD][SEQ][HD] bf16 ; vtb: [NHEAD][HD][SEQ] bf16
// ob: HEAD-MAJOR [NHEAD][SEQ][HD] bf16 (== swapaxes(0,1).reshape order, b=1)
// Each block handles q-tile PAIR (qp, 31-qp) of one head = exactly 33
// KV-tile-computes per block (uniform -> no drain tail). The K/V staging
// stream [0..31-qp] is SHARED: on the common prefix both q-tiles consume the
// same staged tile, with K/V LDS fragments loaded ONCE for two MFMA chains.
// S^T = mfma(K,Q) keeps softmax lane-local (q = lane&15).
__global__ __launch_bounds__(256) void attn_fwd(
    const bf16* __restrict__ qb, const bf16* __restrict__ kb,
    const bf16* __restrict__ vtb, bf16* __restrict__ ob) {
  int p = blockIdx.x;             // 512 = 32 heads x 16 pairs
  int h = p & 31;
  int qp = p >> 5;                // 0..15
  int qtA = qp, qtB = 31 - qp;    // ntA <= 16 < ntB
  __shared__ alignas(16) bf16 Ks[2][64][64];
  __shared__ alignas(16) bf16 Vs[2][64][64];    // V^T tile: [hd][key]
  __shared__ alignas(16) bf16 PsA[4][16][64];   // per-wave P for tile A
  __shared__ alignas(16) bf16 PsB[4][16][64];   // per-wave P for tile B
  int tid = threadIdx.x, lane = tid & 63, w = tid >> 6;
  const bf16* qh = qb + (size_t)h * SEQ * HD;
  const bf16* kh = kb + (size_t)h * SEQ * HD;
  const bf16* vh = vtb + (size_t)h * HD * SEQ;
  int lr = lane & 15, hi = lane >> 4, sw = lr & 7;
  int qrowA = qtA * 64 + w * 16 + lr;
  int qrowB = qtB * 64 + w * 16 + lr;
  bf16x8 qfA[2], qfB[2];
#pragma unroll
  for (int kk = 0; kk < 2; ++kk) {
    qfA[kk] = *(const bf16x8*)(qh + (size_t)qrowA * HD + kk * 32 + hi * 8);
    qfB[kk] = *(const bf16x8*)(qh + (size_t)qrowB * HD + kk * 32 + hi * 8);
  }
  f32x4 otA[4] = {}, otB[4] = {};
  float mA = -3e38f, lA = 0.f, mB = -3e38f, lB = 0.f;
  int ntA = qtA + 1, ntB = qtB + 1;
  int r0 = tid >> 3, sl = tid & 7;
  char* PsWA = (char*)&PsA[w][0][0];
  char* PsWB = (char*)&PsB[w][0][0];

  auto STAGE = [&](int t, int b) {
    int kv0 = t * 64;
#pragma unroll
    for (int i = 0; i < 2; ++i) {
      int row = r0 + 32 * i;
      int kc = sl ^ (row & 7);
      gload16(&Ks[b][row][sl * 8], kh + (size_t)(kv0 + row) * HD + kc * 8);
      gload16(&Vs[b][row][sl * 8], vh + (size_t)row * SEQ + kv0 + kc * 8);
    }
  };

  // softmax update on one state; returns nothing, all lane-local + 2 shuffles
  auto SOFTMAX = [&](f32x4* st, float& mrun, float& lrun, f32x4* ot,
                     bool last, int kv0, int qrow, char* PsW) {
    float tmax = -3e38f;
    if (last) {
#pragma unroll
      for (int n = 0; n < 4; ++n)
#pragma unroll
        for (int j = 0; j < 4; ++j) {
          int key = kv0 + n * 16 + hi * 4 + j;
          float v = (key <= qrow) ? st[n][j] * ATT_SCALE : -1e30f;
          st[n][j] = v;
          tmax = fmaxf(tmax, v);
        }
    } else {
#pragma unroll
      for (int n = 0; n < 4; ++n)
#pragma unroll
        for (int j = 0; j < 4; ++j) {
          float v = st[n][j] * ATT_SCALE;
          st[n][j] = v;
          tmax = fmaxf(tmax, v);
        }
    }
    tmax = fmaxf(tmax, __shfl_xor(tmax, 16));
    tmax = fmaxf(tmax, __shfl_xor(tmax, 32));
    float mnew = fmaxf(mrun, tmax);
    float psum = 0.f;
    if (__all(tmax <= mrun)) {
#pragma unroll
      for (int n = 0; n < 4; ++n)
#pragma unroll
        for (int j = 0; j < 4; ++j) {
          float pv = __expf(st[n][j] - mrun);
          st[n][j] = pv;
          psum += pv;
        }
      psum += __shfl_xor(psum, 16);
      psum += __shfl_xor(psum, 32);
      lrun += psum;
    } else {
      float alpha = __expf(mrun - mnew);
#pragma unroll
      for (int n = 0; n < 4; ++n)
#pragma unroll
        for (int j = 0; j < 4; ++j) {
          float pv = __expf(st[n][j] - mnew);
          st[n][j] = pv;
          psum += pv;
        }
      psum += __shfl_xor(psum, 16);
      psum += __shfl_xor(psum, 32);
      lrun = lrun * alpha + psum;
      mrun = mnew;
#pragma unroll
      for (int nd = 0; nd < 4; ++nd)
#pragma unroll
        for (int j = 0; j < 4; ++j) ot[nd][j] *= alpha;
    }
    // P -> LDS: [q=lr][key], packed 8B, chunk^row&7 swizzle
#pragma unroll
    for (int n = 0; n < 4; ++n) {
      union { bf16 b[4]; uint2 u; } pk;
#pragma unroll
      for (int j = 0; j < 4; ++j) pk.b[j] = (bf16)st[n][j];
      int keyc = n * 2 + (hi >> 1);
      *(uint2*)(PsW + lr * 128 + ((keyc ^ sw) * 16) + (hi & 1) * 8) = pk.u;
    }
  };

  STAGE(0, 0);
  int buf = 0;
  for (int t = 0; t < ntB; ++t) {
    __syncthreads();                        // stage(t) landed; prev reads done
    if (t + 1 < ntB) STAGE(t + 1, buf ^ 1); // prefetch under compute
    int kv0 = t * 64;
    bool doA = (t < ntA);                   // block-uniform branch
    // ---- S^T = K Q^T for both q-tiles, K fragment loaded once
    f32x4 stA[4] = {}, stB[4] = {};
    __builtin_amdgcn_s_setprio(1);
#pragma unroll
    for (int kk = 0; kk < 2; ++kk) {
      int cb = kk * 4 + hi;
#pragma unroll
      for (int n = 0; n < 4; ++n) {
        bf16x8 kf = *(const bf16x8*)&Ks[buf][n * 16 + lr][(cb ^ sw) * 8];
        if (doA) stA[n] = mfma16(kf, qfA[kk], stA[n]);
        stB[n] = mfma16(kf, qfB[kk], stB[n]);
      }
    }
    __builtin_amdgcn_s_setprio(0);
    // ---- two independent softmax chains (interleavable ILP)
    if (doA) SOFTMAX(stA, mA, lA, otA, t == ntA - 1, kv0, qrowA, PsWA);
    SOFTMAX(stB, mB, lB, otB, t == ntB - 1, kv0, qrowB, PsWB);
    // ---- O^T += V^T P for both, V fragment loaded once
    __builtin_amdgcn_s_setprio(1);
#pragma unroll
    for (int kk = 0; kk < 2; ++kk) {
      int cb = kk * 4 + hi;
      bf16x8 pfA = *(const bf16x8*)(PsWA + lr * 128 + ((cb ^ sw) * 16));
      bf16x8 pfB = *(const bf16x8*)(PsWB + lr * 128 + ((cb ^ sw) * 16));
#pragma unroll
      for (int nd = 0; nd < 4; ++nd) {
        bf16x8 vf = *(const bf16x8*)&Vs[buf][nd * 16 + lr][(cb ^ sw) * 8];
        if (doA) otA[nd] = mfma16(vf, pfA, otA[nd]);
        otB[nd] = mfma16(vf, pfB, otB[nd]);
      }
    }
    __builtin_amdgcn_s_setprio(0);
    buf ^= 1;
  }
  // ---- normalize + store head-major, 8B packed
  float rA = 1.0f / lA, rB = 1.0f / lB;
  bf16* orowA = ob + ((size_t)h * SEQ + qrowA) * HD;
  bf16* orowB = ob + ((size_t)h * SEQ + qrowB) * HD;
#pragma unroll
  for (int nd = 0; nd < 4; ++nd) {
    union { bf16 b[4]; uint2 u; } oa, obk;
#pragma unroll
    for (int j = 0; j < 4; ++j) {
      oa.b[j] = (bf16)(otA[nd][j] * rA);
      obk.b[j] = (bf16)(otB[nd][j] * rB);
    }
    *(uint2*)(orowA + nd * 16 + hi * 4) = oa.u;
    *(uint2*)(orowB + nd * 16 + hi * 4) = obk.u;
  }
}

extern "C" void kernel_launch(void* const* d_in, const int* in_sizes, int n_in,
                              void* d_out, int out_size, void* d_ws, size_t ws_size,
                              hipStream_t stream) {
  const float* hs     = (const float*)d_in[0];
  const float* fc     = (const float*)d_in[1];
  const float* fs     = (const float*)d_in[2];
  // d_in[3] = attention_mask (analytic causal; unused)
  const float* kcache = (const float*)d_in[4];
  const float* vcache = (const float*)d_in[5];
  const float* kmask  = (const float*)d_in[6];
  const float* vmask  = (const float*)d_in[7];
  const float* wq     = (const float*)d_in[8];
  const float* wk     = (const float*)d_in[9];
  const float* wv     = (const float*)d_in[10];
  const float* wo     = (const float*)d_in[11];

  float* y    = (float*)d_out;
  float* kout = y + (size_t)SEQ * DIM;
  float* vout = y + 2 * (size_t)SEQ * DIM;

  char* ws = (char*)d_ws;
  const size_t MB8 = (size_t)SEQ * DIM * sizeof(bf16);  // 8 MiB
  bf16* wqT  = (bf16*)(ws + 0 * MB8);
  bf16* wkT  = (bf16*)(ws + 1 * MB8);
  bf16* wvT  = (bf16*)(ws + 2 * MB8);
  bf16* woT  = (bf16*)(ws + 3 * MB8);
  bf16* hsb  = (bf16*)(ws + 4 * MB8);
  bf16* qraw = (bf16*)(ws + 5 * MB8);
  bf16* kraw = (bf16*)(ws + 6 * MB8);
  bf16* vraw = (bf16*)(ws + 7 * MB8);
  bf16* qb   = (bf16*)(ws + 8 * MB8);
  bf16* kb   = (bf16*)(ws + 9 * MB8);
  bf16* vtb  = (bf16*)(ws + 10 * MB8);
  bf16* ob   = hsb;  // hsb dead after QKV GEMM; reuse for attention output
  float* p0 = (float*)(ws + 5 * MB8);   // qraw/kraw dead after ropeqk
  float* p1 = (float*)(ws + 7 * MB8);   // vraw/qb dead after attn

  cvt_hs<<<dim3(SEQ * DIM / 2048), dim3(256), 0, stream>>>(hs, hsb);
  wtrans<<<dim3(32, 32, 4), dim3(256), 0, stream>>>(wq, wk, wv, wo, wqT, wkT, wvT, woT);
  gemm128<bf16><<<dim3(16, 16, 3), dim3(256), 0, stream>>>(
      hsb, wqT, wkT, wvT, qraw, kraw, vraw, SEQ, DIM, DIM);
  ropeqk<<<dim3(SEQ), dim3(256), 0, stream>>>(qraw, kraw, fc, fs, kcache, kmask, kout, qb, kb);
  vprep<<<dim3(32, 32), dim3(256), 0, stream>>>(vraw, vcache, vmask, vout, vtb);
  attn_fwd<<<dim3(512), dim3(256), 0, stream>>>(qb, kb, vtb, ob);
  gemm_osk<<<dim3(16, 16, 2), dim3(256), 0, stream>>>(ob, woT, p0, p1);
  addp<<<dim3(SEQ * DIM / 1024), dim3(256), 0, stream>>>(p0, p1, y);
}

// Round 7
// 200.016 us; speedup vs baseline: 1.2363x; 1.2363x over previous
//
#include <hip/hip_runtime.h>
#include <hip/hip_bf16.h>
#include <stdint.h>

typedef __bf16 bf16;
typedef __attribute__((ext_vector_type(8))) __bf16 bf16x8;
typedef __attribute__((ext_vector_type(4))) float f32x4;

#define SEQ 2048
#define DIM 2048
#define NHEAD 32
#define HD 64
#define ATT_SCALE 0.125f

__device__ __forceinline__ void gload16(void* lds, const void* g) {
  __builtin_amdgcn_global_load_lds(
      (const __attribute__((address_space(1))) unsigned int*)g,
      (__attribute__((address_space(3))) unsigned int*)lds, 16, 0, 0);
}

__device__ __forceinline__ f32x4 mfma16(bf16x8 a, bf16x8 b, f32x4 c) {
  return __builtin_amdgcn_mfma_f32_16x16x32_bf16(a, b, c, 0, 0, 0);
}

// ---------------- elementwise f32 -> bf16 ----------------
__global__ __launch_bounds__(256) void cvt_hs(const float* __restrict__ in,
                                              bf16* __restrict__ out) {
  size_t i = ((size_t)blockIdx.x * 256 + threadIdx.x) * 8;
  f32x4 a = *(const f32x4*)(in + i);
  f32x4 b = *(const f32x4*)(in + i + 4);
  bf16x8 o;
#pragma unroll
  for (int j = 0; j < 4; ++j) { o[j] = (bf16)a[j]; o[j + 4] = (bf16)b[j]; }
  *(bf16x8*)(out + i) = o;
}

// ---------------- weight transpose + convert: wT[n][k] = bf16(w[k][n]) ----------------
__global__ __launch_bounds__(256) void wtrans(
    const float* __restrict__ w0, const float* __restrict__ w1,
    const float* __restrict__ w2, const float* __restrict__ w3,
    bf16* __restrict__ t0, bf16* __restrict__ t1,
    bf16* __restrict__ t2, bf16* __restrict__ t3) {
  const float* wsrc[4] = {w0, w1, w2, w3};
  bf16* wdst[4] = {t0, t1, t2, t3};
  const float* w = wsrc[blockIdx.z];
  bf16* wT = wdst[blockIdx.z];
  __shared__ alignas(16) bf16 tile[64][72];
  int t = threadIdx.x;
  int n0 = blockIdx.x * 64, k0 = blockIdx.y * 64;
#pragma unroll
  for (int i = 0; i < 4; ++i) {
    int r = (t >> 4) + 16 * i;       // k offset
    int c = (t & 15) * 4;            // n offset
    f32x4 v = *(const f32x4*)(w + (size_t)(k0 + r) * DIM + n0 + c);
#pragma unroll
    for (int j = 0; j < 4; ++j) tile[r][c + j] = (bf16)v[j];
  }
  __syncthreads();
#pragma unroll
  for (int i = 0; i < 2; ++i) {
    int n = (t >> 3) + 32 * i;
    int kb = (t & 7) * 8;
    bf16x8 o;
#pragma unroll
    for (int j = 0; j < 8; ++j) o[j] = tile[kb + j][n];
    *(bf16x8*)(wT + (size_t)(n0 + n) * DIM + k0 + kb) = o;
  }
}

// ---------------- 128x128 bf16 GEMM, C = A @ Bt^T  (A: MxK, Bt: NxK) ----------------
template <typename OutT>
__global__ __launch_bounds__(256) void gemm128(
    const bf16* __restrict__ A,
    const bf16* __restrict__ B0, const bf16* __restrict__ B1, const bf16* __restrict__ B2,
    OutT* __restrict__ C0, OutT* __restrict__ C1, OutT* __restrict__ C2,
    int M, int N, int K) {
  const bf16* Bt; OutT* C;
  if (blockIdx.z == 0)      { Bt = B0; C = C0; }
  else if (blockIdx.z == 1) { Bt = B1; C = C1; }
  else                      { Bt = B2; C = C2; }
  __shared__ alignas(16) bf16 As[128][64];
  __shared__ alignas(16) bf16 Bs[128][64];
  int tid = threadIdx.x, lane = tid & 63, w = tid >> 6;
  int wr = w >> 1, wc = w & 1;
  size_t mBase = (size_t)blockIdx.y * 128, nBase = (size_t)blockIdx.x * 128;
  f32x4 acc[4][4] = {};
  int r0 = tid >> 3, sl = tid & 7;
  int lr = lane & 15, hi = lane >> 4, sw = lr & 7;
  for (int kt = 0; kt < K; kt += 64) {
#pragma unroll
    for (int i = 0; i < 4; ++i) {
      int row = r0 + 32 * i;
      int kc = sl ^ (row & 7);
      gload16(&As[row][sl * 8], A + (mBase + row) * K + kt + kc * 8);
      gload16(&Bs[row][sl * 8], Bt + (nBase + row) * K + kt + kc * 8);
    }
    __syncthreads();
#pragma unroll
    for (int kk = 0; kk < 2; ++kk) {
      int cb = kk * 4 + hi;
      bf16x8 a[4], b[4];
#pragma unroll
      for (int m = 0; m < 4; ++m)
        a[m] = *(const bf16x8*)&As[wr * 64 + m * 16 + lr][(cb ^ sw) * 8];
#pragma unroll
      for (int n = 0; n < 4; ++n)
        b[n] = *(const bf16x8*)&Bs[wc * 64 + n * 16 + lr][(cb ^ sw) * 8];
#pragma unroll
      for (int m = 0; m < 4; ++m)
#pragma unroll
        for (int n = 0; n < 4; ++n)
          acc[m][n] = mfma16(a[m], b[n], acc[m][n]);
    }
    __syncthreads();
  }
#pragma unroll
  for (int m = 0; m < 4; ++m)
#pragma unroll
    for (int n = 0; n < 4; ++n)
#pragma unroll
      for (int j = 0; j < 4; ++j) {
        size_t row = mBase + wr * 64 + m * 16 + hi * 4 + j;
        size_t col = nBase + wc * 64 + n * 16 + lr;
        C[row * N + col] = (OutT)acc[m][n][j];
      }
}

// ---- split-K (x2) variant for the 2048x2048 out-projection: 512 blocks ----
__global__ __launch_bounds__(256) void gemm_osk(
    const bf16* __restrict__ A, const bf16* __restrict__ Bt,
    float* __restrict__ P0, float* __restrict__ P1) {
  const int K = DIM, N = DIM;
  float* C = blockIdx.z ? P1 : P0;
  int kbeg = blockIdx.z * (K / 2), kend = kbeg + K / 2;
  __shared__ alignas(16) bf16 As[128][64];
  __shared__ alignas(16) bf16 Bs[128][64];
  int tid = threadIdx.x, lane = tid & 63, w = tid >> 6;
  int wr = w >> 1, wc = w & 1;
  size_t mBase = (size_t)blockIdx.y * 128, nBase = (size_t)blockIdx.x * 128;
  f32x4 acc[4][4] = {};
  int r0 = tid >> 3, sl = tid & 7;
  int lr = lane & 15, hi = lane >> 4, sw = lr & 7;
  for (int kt = kbeg; kt < kend; kt += 64) {
#pragma unroll
    for (int i = 0; i < 4; ++i) {
      int row = r0 + 32 * i;
      int kc = sl ^ (row & 7);
      gload16(&As[row][sl * 8], A + (mBase + row) * K + kt + kc * 8);
      gload16(&Bs[row][sl * 8], Bt + (nBase + row) * K + kt + kc * 8);
    }
    __syncthreads();
#pragma unroll
    for (int kk = 0; kk < 2; ++kk) {
      int cb = kk * 4 + hi;
      bf16x8 a[4], b[4];
#pragma unroll
      for (int m = 0; m < 4; ++m)
        a[m] = *(const bf16x8*)&As[wr * 64 + m * 16 + lr][(cb ^ sw) * 8];
#pragma unroll
      for (int n = 0; n < 4; ++n)
        b[n] = *(const bf16x8*)&Bs[wc * 64 + n * 16 + lr][(cb ^ sw) * 8];
#pragma unroll
      for (int m = 0; m < 4; ++m)
#pragma unroll
        for (int n = 0; n < 4; ++n)
          acc[m][n] = mfma16(a[m], b[n], acc[m][n]);
    }
    __syncthreads();
  }
#pragma unroll
  for (int m = 0; m < 4; ++m)
#pragma unroll
    for (int n = 0; n < 4; ++n)
#pragma unroll
      for (int j = 0; j < 4; ++j) {
        size_t row = mBase + wr * 64 + m * 16 + hi * 4 + j;
        size_t col = nBase + wc * 64 + n * 16 + lr;
        C[row * N + col] = acc[m][n][j];
      }
}

// ---- y = p0 + p1 (split-K reduce), vectorized ----
__global__ __launch_bounds__(256) void addp(const float* __restrict__ a,
                                            const float* __restrict__ b,
                                            float* __restrict__ y) {
  size_t i = ((size_t)blockIdx.x * 256 + threadIdx.x) * 4;
  f32x4 va = *(const f32x4*)(a + i);
  f32x4 vb = *(const f32x4*)(b + i);
  *(f32x4*)(y + i) = va + vb;
}

// ---------------- RoPE for q,k + k blend; writes head-major bf16 + f32 k out ----------------
__global__ __launch_bounds__(256) void ropeqk(
    const bf16* __restrict__ qraw, const bf16* __restrict__ kraw,
    const float* __restrict__ fc, const float* __restrict__ fs,
    const float* __restrict__ kcache, const float* __restrict__ kmask,
    float* __restrict__ kout, bf16* __restrict__ qb, bf16* __restrict__ kb) {
  int s = blockIdx.x;
  float km = kmask[s];
  float omk = 1.0f - km;
  for (int p = threadIdx.x; p < DIM / 2; p += 256) {
    int h = p >> 5, i = p & 31;
    float c = fc[s * 32 + i], sn = fs[s * 32 + i];
    size_t src = (size_t)s * DIM + h * 64 + 2 * i;
    float xr = (float)qraw[src], xi = (float)qraw[src + 1];
    float q0v = xr * c - xi * sn, q1v = xr * sn + xi * c;
    size_t dsth = (size_t)h * SEQ * HD + (size_t)s * HD + 2 * i;
    qb[dsth] = (bf16)q0v; qb[dsth + 1] = (bf16)q1v;
    xr = (float)kraw[src]; xi = (float)kraw[src + 1];
    float k0v = xr * c - xi * sn, k1v = xr * sn + xi * c;
    float b0 = kcache[src] * omk + k0v * km;
    float b1 = kcache[src + 1] * omk + k1v * km;
    kout[src] = b0; kout[src + 1] = b1;
    kb[dsth] = (bf16)b0; kb[dsth + 1] = (bf16)b1;
  }
}

// ---------------- v blend + f32 out + per-head transpose to vT[h][hd][s] ----------------
__global__ __launch_bounds__(256) void vprep(
    const bf16* __restrict__ vraw, const float* __restrict__ vcache,
    const float* __restrict__ vmask, float* __restrict__ vout,
    bf16* __restrict__ vtb) {
  int h = blockIdx.y;
  int s0 = blockIdx.x * 64;
  __shared__ alignas(16) bf16 tile[64][72];
  int t = threadIdx.x;
#pragma unroll
  for (int i = 0; i < 4; ++i) {
    int r = (t >> 4) + 16 * i;   // s offset
    int c = (t & 15) * 4;        // hd offset
    int s = s0 + r;
    float vm = vmask[s], om = 1.0f - vm;
    size_t src = (size_t)s * DIM + h * 64 + c;
    f32x4 vc = *(const f32x4*)(vcache + src);
    f32x4 o;
#pragma unroll
    for (int j = 0; j < 4; ++j) {
      float val = vc[j] * om + (float)vraw[src + j] * vm;
      o[j] = val;
      tile[r][c + j] = (bf16)val;
    }
    *(f32x4*)(vout + src) = o;
  }
  __syncthreads();
#pragma unroll
  for (int i = 0; i < 2; ++i) {
    int hd = (t >> 3) + 32 * i;
    int cb = (t & 7) * 8;
    bf16x8 o;
#pragma unroll
    for (int j = 0; j < 8; ++j) o[j] = tile[cb + j][hd];
    *(bf16x8*)(vtb + (size_t)h * HD * SEQ + (size_t)hd * SEQ + s0 + cb) = o;
  }
}

// ---------------- causal flash attention: flat 33-iteration paired loop ----
// qb,kb: [NHEAD][SEQ][HD] bf16 ; vtb: [NHEAD][HD][SEQ] bf16
// ob: HEAD-MAJOR [NHEAD][SEQ][HD] bf16 (== swapaxes(0,1).reshape order, b=1)
// 512 blocks; block handles q-tiles qp and 31-qp SEQUENTIALLY in ONE flat
// loop of exactly (qp+1)+(32-qp) = 33 KV-tile iterations -> every block does
// identical work (no drain tail), one state set hot at a time (VGPR ~= R3).
// K/V double-buffer + prefetch runs seamlessly across the segment boundary.
// XCD swizzle: 64 consecutive wg (= 4 heads) per XCD -> K/V L2-resident.
// S^T = mfma(K,Q) keeps softmax lane-local (q = lane&15).
__global__ __launch_bounds__(256) void attn_fwd(
    const bf16* __restrict__ qb, const bf16* __restrict__ kb,
    const bf16* __restrict__ vtb, bf16* __restrict__ ob) {
  int orig = blockIdx.x;                 // 512 blocks, 512%8==0 -> bijective
  int wg = (orig & 7) * 64 + (orig >> 3);
  int h = wg >> 4;                       // 4 consecutive heads per XCD
  int qp = wg & 15;
  int qtA = qp, qtB = 31 - qp;
  int ntA = qtA + 1;                     // flat loop: A tiles [0,ntA), B tiles [ntA,33)
  const int NT = 33;
  __shared__ alignas(16) bf16 Ks[2][64][64];
  __shared__ alignas(16) bf16 Vs[2][64][64];   // V^T tile: [hd][key]
  __shared__ alignas(16) bf16 Ps[4][16][64];   // per-wave P: [q][key]
  int tid = threadIdx.x, lane = tid & 63, w = tid >> 6;
  const bf16* qh = qb + (size_t)h * SEQ * HD;
  const bf16* kh = kb + (size_t)h * SEQ * HD;
  const bf16* vh = vtb + (size_t)h * HD * SEQ;
  int lr = lane & 15, hi = lane >> 4, sw = lr & 7;
  int qrowA = qtA * 64 + w * 16 + lr;
  int qrowB = qtB * 64 + w * 16 + lr;
  bf16x8 qfA[2], qfB[2];
#pragma unroll
  for (int kk = 0; kk < 2; ++kk) {
    qfA[kk] = *(const bf16x8*)(qh + (size_t)qrowA * HD + kk * 32 + hi * 8);
    qfB[kk] = *(const bf16x8*)(qh + (size_t)qrowB * HD + kk * 32 + hi * 8);
  }
  f32x4 otA[4] = {}, otB[4] = {};
  float mA = -3e38f, lA = 0.f, mB = -3e38f, lB = 0.f;
  int r0 = tid >> 3, sl = tid & 7;
  char* PsW = (char*)&Ps[w][0][0];

  auto STAGE = [&](int kv0, int b) {
#pragma unroll
    for (int i = 0; i < 2; ++i) {
      int row = r0 + 32 * i;
      int kc = sl ^ (row & 7);
      gload16(&Ks[b][row][sl * 8], kh + (size_t)(kv0 + row) * HD + kc * 8);
      gload16(&Vs[b][row][sl * 8], vh + (size_t)row * SEQ + kv0 + kc * 8);
    }
  };

  // full per-tile body for one q-tile state (lane-local softmax, P->LDS, PV)
  auto BODY = [&](int buf, int kv0, bf16x8 (&qf)[2], f32x4 (&ot)[4],
                  float& mrun, float& lrun, int qrow, bool last) {
    f32x4 st[4] = {};
    __builtin_amdgcn_s_setprio(1);
#pragma unroll
    for (int kk = 0; kk < 2; ++kk) {
      int cb = kk * 4 + hi;
#pragma unroll
      for (int n = 0; n < 4; ++n) {
        bf16x8 kf = *(const bf16x8*)&Ks[buf][n * 16 + lr][(cb ^ sw) * 8];
        st[n] = mfma16(kf, qf[kk], st[n]);
      }
    }
    __builtin_amdgcn_s_setprio(0);
    float tmax = -3e38f;
    if (last) {
#pragma unroll
      for (int n = 0; n < 4; ++n)
#pragma unroll
        for (int j = 0; j < 4; ++j) {
          int key = kv0 + n * 16 + hi * 4 + j;
          float v = (key <= qrow) ? st[n][j] * ATT_SCALE : -1e30f;
          st[n][j] = v;
          tmax = fmaxf(tmax, v);
        }
    } else {
#pragma unroll
      for (int n = 0; n < 4; ++n)
#pragma unroll
        for (int j = 0; j < 4; ++j) {
          float v = st[n][j] * ATT_SCALE;
          st[n][j] = v;
          tmax = fmaxf(tmax, v);
        }
    }
    tmax = fmaxf(tmax, __shfl_xor(tmax, 16));
    tmax = fmaxf(tmax, __shfl_xor(tmax, 32));
    float mnew = fmaxf(mrun, tmax);
    float psum = 0.f;
    if (__all(tmax <= mrun)) {
#pragma unroll
      for (int n = 0; n < 4; ++n)
#pragma unroll
        for (int j = 0; j < 4; ++j) {
          float pv = __expf(st[n][j] - mrun);
          st[n][j] = pv;
          psum += pv;
        }
      psum += __shfl_xor(psum, 16);
      psum += __shfl_xor(psum, 32);
      lrun += psum;
    } else {
      float alpha = __expf(mrun - mnew);
#pragma unroll
      for (int n = 0; n < 4; ++n)
#pragma unroll
        for (int j = 0; j < 4; ++j) {
          float pv = __expf(st[n][j] - mnew);
          st[n][j] = pv;
          psum += pv;
        }
      psum += __shfl_xor(psum, 16);
      psum += __shfl_xor(psum, 32);
      lrun = lrun * alpha + psum;
      mrun = mnew;
#pragma unroll
      for (int nd = 0; nd < 4; ++nd)
#pragma unroll
        for (int j = 0; j < 4; ++j) ot[nd][j] *= alpha;
    }
#pragma unroll
    for (int n = 0; n < 4; ++n) {
      union { bf16 b[4]; uint2 u; } pk;
#pragma unroll
      for (int j = 0; j < 4; ++j) pk.b[j] = (bf16)st[n][j];
      int keyc = n * 2 + (hi >> 1);
      *(uint2*)(PsW + lr * 128 + ((keyc ^ sw) * 16) + (hi & 1) * 8) = pk.u;
    }
    __builtin_amdgcn_s_setprio(1);
#pragma unroll
    for (int kk = 0; kk < 2; ++kk) {
      int cb = kk * 4 + hi;
      bf16x8 pf = *(const bf16x8*)(PsW + lr * 128 + ((cb ^ sw) * 16));
#pragma unroll
      for (int nd = 0; nd < 4; ++nd) {
        bf16x8 vf = *(const bf16x8*)&Vs[buf][nd * 16 + lr][(cb ^ sw) * 8];
        ot[nd] = mfma16(vf, pf, ot[nd]);
      }
    }
    __builtin_amdgcn_s_setprio(0);
  };

  auto STORE = [&](f32x4 (&ot)[4], float lrun, int qrow) {
    float rinv = 1.0f / lrun;
    bf16* orow = ob + ((size_t)h * SEQ + qrow) * HD;
#pragma unroll
    for (int nd = 0; nd < 4; ++nd) {
      union { bf16 b[4]; uint2 u; } o;
#pragma unroll
      for (int j = 0; j < 4; ++j) o.b[j] = (bf16)(ot[nd][j] * rinv);
      *(uint2*)(orow + nd * 16 + hi * 4) = o.u;
    }
  };

  STAGE(0, 0);
  int buf = 0;
  for (int t = 0; t < NT; ++t) {
    __syncthreads();                 // stage(t) landed; all reads of buf done
    if (t + 1 < NT) {
      int tn = t + 1;
      int kvn = (tn < ntA ? tn : tn - ntA) * 64;
      STAGE(kvn, buf ^ 1);           // prefetch flies under compute
    }
    if (t < ntA) {                   // segment A (wave-uniform branch)
      int kv0 = t * 64;
      BODY(buf, kv0, qfA, otA, mA, lA, qrowA, t == ntA - 1);
      if (t == ntA - 1) STORE(otA, lA, qrowA);  // A state dies here
    } else {                         // segment B
      int kv0 = (t - ntA) * 64;
      BODY(buf, kv0, qfB, otB, mB, lB, qrowB, t == NT - 1);
    }
    buf ^= 1;
  }
  STORE(otB, lB, qrowB);
}

extern "C" void kernel_launch(void* const* d_in, const int* in_sizes, int n_in,
                              void* d_out, int out_size, void* d_ws, size_t ws_size,
                              hipStream_t stream) {
  const float* hs     = (const float*)d_in[0];
  const float* fc     = (const float*)d_in[1];
  const float* fs     = (const float*)d_in[2];
  // d_in[3] = attention_mask (analytic causal; unused)
  const float* kcache = (const float*)d_in[4];
  const float* vcache = (const float*)d_in[5];
  const float* kmask  = (const float*)d_in[6];
  const float* vmask  = (const float*)d_in[7];
  const float* wq     = (const float*)d_in[8];
  const float* wk     = (const float*)d_in[9];
  const float* wv     = (const float*)d_in[10];
  const float* wo     = (const float*)d_in[11];

  float* y    = (float*)d_out;
  float* kout = y + (size_t)SEQ * DIM;
  float* vout = y + 2 * (size_t)SEQ * DIM;

  char* ws = (char*)d_ws;
  const size_t MB8 = (size_t)SEQ * DIM * sizeof(bf16);  // 8 MiB
  bf16* wqT  = (bf16*)(ws + 0 * MB8);
  bf16* wkT  = (bf16*)(ws + 1 * MB8);
  bf16* wvT  = (bf16*)(ws + 2 * MB8);
  bf16* woT  = (bf16*)(ws + 3 * MB8);
  bf16* hsb  = (bf16*)(ws + 4 * MB8);
  bf16* qraw = (bf16*)(ws + 5 * MB8);
  bf16* kraw = (bf16*)(ws + 6 * MB8);
  bf16* vraw = (bf16*)(ws + 7 * MB8);
  bf16* qb   = (bf16*)(ws + 8 * MB8);
  bf16* kb   = (bf16*)(ws + 9 * MB8);
  bf16* vtb  = (bf16*)(ws + 10 * MB8);
  bf16* ob   = hsb;  // hsb dead after QKV GEMM; reuse for attention output
  float* p0 = (float*)(ws + 5 * MB8);   // qraw/kraw dead after ropeqk
  float* p1 = (float*)(ws + 7 * MB8);   // vraw/qb dead after attn

  cvt_hs<<<dim3(SEQ * DIM / 2048), dim3(256), 0, stream>>>(hs, hsb);
  wtrans<<<dim3(32, 32, 4), dim3(256), 0, stream>>>(wq, wk, wv, wo, wqT, wkT, wvT, woT);
  gemm128<bf16><<<dim3(16, 16, 3), dim3(256), 0, stream>>>(
      hsb, wqT, wkT, wvT, qraw, kraw, vraw, SEQ, DIM, DIM);
  ropeqk<<<dim3(SEQ), dim3(256), 0, stream>>>(qraw, kraw, fc, fs, kcache, kmask, kout, qb, kb);
  vprep<<<dim3(32, 32), dim3(256), 0, stream>>>(vraw, vcache, vmask, vout, vtb);
  attn_fwd<<<dim3(512), dim3(256), 0, stream>>>(qb, kb, vtb, ob);
  gemm_osk<<<dim3(16, 16, 2), dim3(256), 0, stream>>>(ob, woT, p0, p1);
  addp<<<dim3(SEQ * DIM / 1024), dim3(256), 0, stream>>>(p0, p1, y);
}